// Round 4
// baseline (39.324 us; speedup 1.0000x reference)
//
#include <hip/hip_runtime.h>

constexpr int Bc = 4, Nc = 16384, Mc = 4096, Kc = 32;
constexpr float EPSc = 1e-5f;
constexpr float L2E = 1.4426950408889634f;   // log2(e)

using bf16x8 = __attribute__((ext_vector_type(8))) short;   // 8 bf16 (4 VGPRs)
using f32x4  = __attribute__((ext_vector_type(4))) float;   // 4 fp32

// round-to-nearest-even fp32 -> bf16 bits
__device__ inline unsigned f2bf_bits(float x) {
    unsigned u = __float_as_uint(x);
    return (u + 0x7fffu + ((u >> 16) & 1u)) >> 16;
}
__device__ inline short f2bf(float x) { return (short)f2bf_bits(x); }

// ---------------------------------------------------------------------------
// Phase A (MFMA): Sfa[b*N+n][c] = pack( hi=bf16(BN(feats@Wf)[c]*log2e),
//                                       lo=bf16(BN(feats@Wa)[c]) )
// Feat plane pre-scaled by log2e so phase B uses raw exp2 (no max-sub needed).
// ---------------------------------------------------------------------------
__global__ __launch_bounds__(256) void pt_encode(
    const float* __restrict__ feats,
    const float* __restrict__ Wf, const float* __restrict__ Wa,
    const float* __restrict__ fg, const float* __restrict__ fb,
    const float* __restrict__ fm, const float* __restrict__ fv,
    const float* __restrict__ ag, const float* __restrict__ ab,
    const float* __restrict__ am, const float* __restrict__ av,
    unsigned* __restrict__ Sfa)
{
    __shared__ __align__(16) short WT[128][72];   // [col][k], pad 64->72
    __shared__ float scl[128], bis[128];
    const int tid = threadIdx.x;
    if (tid < 128) {
        const int c = tid & 63;
        const float g  = (tid < 64) ? fg[c] : ag[c];
        const float v  = (tid < 64) ? fv[c] : av[c];
        const float bb = (tid < 64) ? fb[c] : ab[c];
        const float mm = (tid < 64) ? fm[c] : am[c];
        const float s = g * rsqrtf(v + EPSc);
        scl[tid] = (tid < 64) ? s * L2E : s;
        bis[tid] = (tid < 64) ? (bb - mm * s) * L2E : (bb - mm * s);
    }
    __syncthreads();
#pragma unroll
    for (int i = 0; i < 16; ++i) {
        const int idx = tid + 256 * i;          // (k,c) = (idx>>6, idx&63)
        const int k = idx >> 6, c = idx & 63;
        WT[c][k]      = f2bf(Wf[idx] * scl[c]);
        WT[64 + c][k] = f2bf(Wa[idx] * scl[64 + c]);
    }
    __syncthreads();

    const int lane = tid & 63, w = tid >> 6;
    const int row16 = lane & 15, kg = lane >> 4;

    bf16x8 bfr[8][2];                            // B frags: lane holds W[k][col]
#pragma unroll
    for (int t = 0; t < 8; ++t)
#pragma unroll
        for (int h = 0; h < 2; ++h)
            bfr[t][h] = *(const bf16x8*)&WT[16 * t + row16][32 * h + kg * 8];

    const long long pt = (long long)blockIdx.x * 4 + w;   // 4096 point-tiles
    const long long base = pt * 16;
    const float* arow = feats + (base + row16) * 64 + kg * 8;
    const float4 v0 = *(const float4*)(arow + 0);
    const float4 v1 = *(const float4*)(arow + 4);
    const float4 v2 = *(const float4*)(arow + 32);
    const float4 v3 = *(const float4*)(arow + 36);
    bf16x8 af0, af1;
    af0[0] = f2bf(v0.x); af0[1] = f2bf(v0.y); af0[2] = f2bf(v0.z); af0[3] = f2bf(v0.w);
    af0[4] = f2bf(v1.x); af0[5] = f2bf(v1.y); af0[6] = f2bf(v1.z); af0[7] = f2bf(v1.w);
    af1[0] = f2bf(v2.x); af1[1] = f2bf(v2.y); af1[2] = f2bf(v2.z); af1[3] = f2bf(v2.w);
    af1[4] = f2bf(v3.x); af1[5] = f2bf(v3.y); af1[6] = f2bf(v3.z); af1[7] = f2bf(v3.w);

    f32x4 acc[8];
#pragma unroll
    for (int t = 0; t < 8; ++t) {
        f32x4 z = {0.f, 0.f, 0.f, 0.f};
        z = __builtin_amdgcn_mfma_f32_16x16x32_bf16(af0, bfr[t][0], z, 0, 0, 0);
        z = __builtin_amdgcn_mfma_f32_16x16x32_bf16(af1, bfr[t][1], z, 0, 0, 0);
        acc[t] = z;
    }
    // C/D layout: row=(lane>>4)*4+reg, col=lane&15
#pragma unroll
    for (int t = 0; t < 4; ++t) {
        const int c = 16 * t + row16;
        const float bfv = bis[c], bav = bis[64 + c];
#pragma unroll
        for (int r = 0; r < 4; ++r) {
            const unsigned u = f2bf_bits(acc[t + 4][r] + bav)            // lo = attn
                             | (f2bf_bits(acc[t][r] + bfv) << 16);       // hi = feat*log2e
            Sfa[(base + kg * 4 + r) * 64 + c] = u;
        }
    }
}

// ---------------------------------------------------------------------------
// Phase B+C: 512 threads = 8 waves, ONE group per wave (8 groups/block).
// All 32 gathers issued up-front into registers (SGPR row base via
// readfirstlane); Wr->LDS staging runs while the gathers are in flight.
// Then exp2-domain softmax, snf -> LDS, 8-row refine MFMA + BN/ReLU/mask.
// Block swizzle pins batch b to XCD pair {2b,2b+1} (4 MB working set/XCD).
// ---------------------------------------------------------------------------
__global__ __launch_bounds__(512, 6) void pt_gr(
    const float* __restrict__ xyz, const float* __restrict__ nxyz,
    const unsigned* __restrict__ Sfa,
    const float* __restrict__ Wx,
    const float* __restrict__ xg, const float* __restrict__ xb,
    const float* __restrict__ xm, const float* __restrict__ xv,
    const float* __restrict__ Wr,
    const float* __restrict__ rg, const float* __restrict__ rb,
    const float* __restrict__ rm, const float* __restrict__ rv,
    const int* __restrict__ gidx, const int* __restrict__ gcnt,
    float* __restrict__ out)
{
    __shared__ __align__(16) short WT[128][72];   // refine weights [col][k]
    __shared__ float scl_[128], bis[128];
    __shared__ __align__(16) short snf[16][72];   // rows 0-7 = groups, 8-15 = zero
    __shared__ int    sidx[8][32];
    __shared__ float4 sxyz[8][32];

    const int tid = threadIdx.x, lane = tid & 63, w = tid >> 6;

    // bijective XCD-pinning swizzle: xcd = blk%8 serves batch (blk%8)>>1
    const int i = blockIdx.x;                     // 0..2047
    const int b = (i & 7) >> 1;
    const int j = ((i >> 3) << 1) | (i & 1);      // 0..511 tile within batch
    const long long gbase = (long long)b * Mc + j * 8;

    if (tid < 128) {
        const float s = rg[tid] * rsqrtf(rv[tid] + EPSc);
        scl_[tid] = s;
        bis[tid] = rb[tid] - rm[tid] * s;
    }
    if (tid < 256) {   // stage neighbor indices + xyz: one (group,k) per thread
        const int gi = tid >> 5, kk = tid & 31;
        const int n = gidx[(gbase + gi) * 32 + kk];
        sidx[gi][kk] = n;
        const float* xp = xyz + ((long long)b * Nc + n) * 3;
        sxyz[gi][kk] = make_float4(xp[0], xp[1], xp[2], 0.f);
    }
    __syncthreads();

    // -- issue ALL 32 gathers for this wave's group (SGPR base + lane offset)
    const unsigned* sbase = Sfa + (long long)b * (Nc * 64);
    unsigned d[32];
#pragma unroll
    for (int k = 0; k < Kc; ++k) {
        const int n = __builtin_amdgcn_readfirstlane(sidx[w][k]);
        d[k] = sbase[((long long)n << 6) + lane];
    }

    // -- stage Wr * scale as bf16^T while the gathers are in flight
#pragma unroll
    for (int it = 0; it < 16; ++it) {
        const int idx = tid + 512 * it;           // (k,c) = (idx>>7, idx&127)
        WT[idx & 127][idx >> 7] = f2bf(Wr[idx] * scl_[idx & 127]);
    }

    // per-lane channel coeffs (lane == channel)
    const float xs = xg[lane] * rsqrtf(xv[lane] + EPSc);
    const float w0 = Wx[lane] * xs, w1 = Wx[64 + lane] * xs, w2 = Wx[128 + lane] * xs;
    const float* nx = nxyz + (gbase + w) * 3;
    const float Q = xb[lane] - xm[lane] * xs
                  - fmaf(nx[0], w0, fmaf(nx[1], w1, nx[2] * w2));

    float ss = 0.f, ac = 0.f;
#pragma unroll
    for (int k = 0; k < Kc; ++k) {
        const float4 x = sxyz[w][k];              // LDS broadcast
        const float gx = fmaf(x.x, w0, fmaf(x.y, w1, fmaf(x.z, w2, Q)));
        // hi16 = f*log2e (bf16), lo16 = a (bf16); |f|<<128 so no max-sub
        const float e = __builtin_amdgcn_exp2f(
            fmaf(gx, L2E, __uint_as_float(d[k] & 0xffff0000u)));
        const float a = __uint_as_float(d[k] << 16) + gx;
        ss += e;
        ac = fmaf(e, a, ac);
    }
    snf[w][lane] = f2bf(ac / ss);
    snf[8 + w][lane] = 0;                         // pad rows for the MFMA tile
    __syncthreads();

    // refine MFMA: A = snf (8 valid rows), B = WT col-tile w
    const int row16 = lane & 15, kg = lane >> 4;
    const bf16x8 af0 = *(const bf16x8*)&snf[row16][kg * 8];
    const bf16x8 af1 = *(const bf16x8*)&snf[row16][32 + kg * 8];
    const bf16x8 bf0 = *(const bf16x8*)&WT[16 * w + row16][kg * 8];
    const bf16x8 bf1 = *(const bf16x8*)&WT[16 * w + row16][32 + kg * 8];
    f32x4 z = {0.f, 0.f, 0.f, 0.f};
    z = __builtin_amdgcn_mfma_f32_16x16x32_bf16(af0, bf0, z, 0, 0, 0);
    z = __builtin_amdgcn_mfma_f32_16x16x32_bf16(af1, bf1, z, 0, 0, 0);

    if (kg < 2) {                                 // rows 0-7 are real groups
        const int4 c4 = *(const int4*)(gcnt + gbase + kg * 4);
        const int cc = 16 * w + row16;
        const float bb = bis[cc];
        float* orow = out + (gbase + kg * 4) * 128 + cc;
        orow[0]   = fmaxf(z[0] + bb, 0.f) * (c4.x > 0 ? 1.f : 0.f);
        orow[128] = fmaxf(z[1] + bb, 0.f) * (c4.y > 0 ? 1.f : 0.f);
        orow[256] = fmaxf(z[2] + bb, 0.f) * (c4.z > 0 ? 1.f : 0.f);
        orow[384] = fmaxf(z[3] + bb, 0.f) * (c4.w > 0 ? 1.f : 0.f);
    }
}

extern "C" void kernel_launch(void* const* d_in, const int* in_sizes, int n_in,
                              void* d_out, int out_size, void* d_ws, size_t ws_size,
                              hipStream_t stream)
{
    const float* xyz  = (const float*)d_in[0];
    const float* nxyz = (const float*)d_in[1];
    const float* feats = (const float*)d_in[2];
    const float* Wf = (const float*)d_in[3];
    const float* fg = (const float*)d_in[4];
    const float* fb = (const float*)d_in[5];
    const float* fm = (const float*)d_in[6];
    const float* fv = (const float*)d_in[7];
    const float* Wa = (const float*)d_in[8];
    const float* ag = (const float*)d_in[9];
    const float* ab = (const float*)d_in[10];
    const float* am = (const float*)d_in[11];
    const float* av = (const float*)d_in[12];
    const float* Wx = (const float*)d_in[13];
    const float* xg = (const float*)d_in[14];
    const float* xb = (const float*)d_in[15];
    const float* xm = (const float*)d_in[16];
    const float* xv = (const float*)d_in[17];
    const float* Wr = (const float*)d_in[18];
    const float* rg = (const float*)d_in[19];
    const float* rb = (const float*)d_in[20];
    const float* rm = (const float*)d_in[21];
    const float* rv = (const float*)d_in[22];
    const int* gidx = (const int*)d_in[23];
    const int* gcnt = (const int*)d_in[24];
    float* out = (float*)d_out;

    unsigned* Sfa = (unsigned*)d_ws;   // B*N*64 dwords = 16 MiB packed bf16 pairs

    pt_encode<<<dim3((Bc * Nc / 16) / 4), dim3(256), 0, stream>>>(
        feats, Wf, Wa, fg, fb, fm, fv, ag, ab, am, av, Sfa);
    pt_gr<<<dim3((Bc * Mc) / 8), dim3(512), 0, stream>>>(
        xyz, nxyz, Sfa, Wx, xg, xb, xm, xv,
        Wr, rg, rb, rm, rv, gidx, gcnt, out);
}